// Round 1
// baseline (352.253 us; speedup 1.0000x reference)
//
#include <hip/hip_runtime.h>

#define CN0 200000
#define CN1 100000
#define CN2 50000
#define CM 16
#define CVL 32
#define CK 32
#define CD 64
#define CEPS 1e-12f

__device__ __forceinline__ float lane_bcast(float v, int l) {
    return __int_as_float(__builtin_amdgcn_readlane(__float_as_int(v), l));
}

// Stage 0: ft_lv0[n] = concat(sum_m x[n,m,:], 0.5*(s^2 - sum_m x^2))
// 8 threads per node, each handles a float4 of the VL=32 dims.
__global__ void k_lv0(const float* __restrict__ x, float* __restrict__ ft0) {
    int t = blockIdx.x * blockDim.x + threadIdx.x;
    int n = t >> 3;
    int q = t & 7;
    if (n >= CN0) return;
    const float4* xp = reinterpret_cast<const float4*>(x + (size_t)n * (CM * CVL)) + q;
    float4 s = make_float4(0.f, 0.f, 0.f, 0.f);
    float4 sq = make_float4(0.f, 0.f, 0.f, 0.f);
#pragma unroll
    for (int m = 0; m < CM; ++m) {
        float4 v = xp[m * (CVL / 4)];
        s.x += v.x; s.y += v.y; s.z += v.z; s.w += v.w;
        sq.x += v.x * v.x; sq.y += v.y * v.y; sq.z += v.z * v.z; sq.w += v.w * v.w;
    }
    float4 cr;
    cr.x = 0.5f * (s.x * s.x - sq.x);
    cr.y = 0.5f * (s.y * s.y - sq.y);
    cr.z = 0.5f * (s.z * s.z - sq.z);
    cr.w = 0.5f * (s.w * s.w - sq.w);
    float4* o = reinterpret_cast<float4*>(ft0 + (size_t)n * CD);
    o[q] = s;
    o[8 + q] = cr;
}

// Conv level: per node n -> gather self row + sum of K neighbor rows,
// c = [n0+pool, n0*pool] (128), out = relu(c @ W + b) (64), optional L2-normalize.
// One wave owns one node's 64-dim row (lane = dim). P=4 nodes per wave per
// W-row LDS read to amortize LDS traffic.
template<bool NORM>
__global__ void k_conv(const float* __restrict__ ftin,
                       const int* __restrict__ ids,
                       const int* __restrict__ adj,
                       const float* __restrict__ W,
                       const float* __restrict__ bias,
                       float* __restrict__ ftout,
                       int nNodes) {
    __shared__ float Wl[2 * CD * CD];  // 32 KiB
    __shared__ float bl[CD];
    for (int i = threadIdx.x; i < 2 * CD * CD; i += blockDim.x) Wl[i] = W[i];
    if (threadIdx.x < CD) bl[threadIdx.x] = bias[threadIdx.x];
    __syncthreads();

    const int lane = threadIdx.x & 63;
    const int wave = threadIdx.x >> 6;
    const int wavesPerBlock = blockDim.x >> 6;
    constexpr int P = 4;
    const int batchNodes = wavesPerBlock * P;
    const int nBatches = (nNodes + batchNodes - 1) / batchNodes;

    for (int batch = blockIdx.x; batch < nBatches; batch += gridDim.x) {
        const int nodeBase = batch * batchNodes + wave * P;
        float c0[P], c1[P], acc[P];
#pragma unroll
        for (int p = 0; p < P; ++p) {
            int n = nodeBase + p;
            float n0 = 0.f, pool = 0.f;
            if (n < nNodes) {  // wave-uniform branch
                int id = ids[n];
                n0 = ftin[(size_t)id * CD + lane];
                const int* arow = adj + (size_t)n * CK;
#pragma unroll 8
                for (int k = 0; k < CK; ++k) {
                    pool += ftin[(size_t)arow[k] * CD + lane];
                }
            }
            c0[p] = n0 + pool;   // rows 0..63 of conv vector (this lane's dim)
            c1[p] = n0 * pool;   // rows 64..127
            acc[p] = bl[lane];
        }
        // out[j] = b[j] + sum_i c[i] * W[i][j]; lane j accumulates its column.
#pragma unroll 8
        for (int i = 0; i < CD; ++i) {
            float w0 = Wl[i * CD + lane];
            float w1 = Wl[(CD + i) * CD + lane];
#pragma unroll
            for (int p = 0; p < P; ++p) {
                acc[p] = fmaf(lane_bcast(c0[p], i), w0, acc[p]);
                acc[p] = fmaf(lane_bcast(c1[p], i), w1, acc[p]);
            }
        }
#pragma unroll
        for (int p = 0; p < P; ++p) {
            int n = nodeBase + p;
            if (n >= nNodes) continue;
            float z = fmaxf(acc[p], 0.f);
            if (NORM) {
                float ss = z * z;
#pragma unroll
                for (int off = 32; off >= 1; off >>= 1) ss += __shfl_xor(ss, off);
                float nrm = fmaxf(sqrtf(ss), CEPS);
                ftout[(size_t)n * CD + lane] = z / nrm;
            } else {
                ftout[(size_t)n * CD + lane] = z;
            }
        }
    }
}

extern "C" void kernel_launch(void* const* d_in, const int* in_sizes, int n_in,
                              void* d_out, int out_size, void* d_ws, size_t ws_size,
                              hipStream_t stream) {
    const float* node_feats  = (const float*)d_in[0];
    const int*   node_l1_ids = (const int*)d_in[1];
    const int*   adj1        = (const int*)d_in[2];
    const int*   node2_pos   = (const int*)d_in[3];
    const int*   adj2        = (const int*)d_in[4];
    const float* W1          = (const float*)d_in[5];
    const float* b1          = (const float*)d_in[6];
    const float* W2          = (const float*)d_in[7];
    const float* b2          = (const float*)d_in[8];
    float* out = (float*)d_out;

    float* ft0 = (float*)d_ws;                    // CN0*CD f32 = 51.2 MB
    float* ft1 = ft0 + (size_t)CN0 * CD;          // CN1*CD f32 = 25.6 MB

    int t1 = CN0 * 8;
    k_lv0<<<(t1 + 255) / 256, 256, 0, stream>>>(node_feats, ft0);
    k_conv<false><<<2048, 256, 0, stream>>>(ft0, node_l1_ids, adj1, W1, b1, ft1, CN1);
    k_conv<true><<<2048, 256, 0, stream>>>(ft1, node2_pos, adj2, W2, b2, out, CN2);
}

// Round 2
// 262.548 us; speedup vs baseline: 1.3417x; 1.3417x over previous
//
#include <hip/hip_runtime.h>
#include <hip/hip_fp16.h>

#define CN0 200000
#define CN1 100000
#define CN2 50000
#define CM 16
#define CVL 32
#define CK 32
#define CD 64
#define CEPS 1e-12f

__device__ __forceinline__ float lane_bcast(float v, int l) {
    return __int_as_float(__builtin_amdgcn_readlane(__float_as_int(v), l));
}

union H4 { __half2 h2[2]; uint2 u; };

// Stage 0: ft_lv0[n] = concat(sum_m x[n,m,:], 0.5*(s^2 - sum_m x^2)), fp16 out.
// 8 threads per node, each handles a float4 of the VL=32 dims.
__global__ void k_lv0(const float* __restrict__ x, __half* __restrict__ ft0) {
    int t = blockIdx.x * blockDim.x + threadIdx.x;
    int n = t >> 3;
    int q = t & 7;
    if (n >= CN0) return;
    const float4* xp = reinterpret_cast<const float4*>(x + (size_t)n * (CM * CVL)) + q;
    float4 s = make_float4(0.f, 0.f, 0.f, 0.f);
    float4 sq = make_float4(0.f, 0.f, 0.f, 0.f);
#pragma unroll
    for (int m = 0; m < CM; ++m) {
        float4 v = xp[m * (CVL / 4)];
        s.x += v.x; s.y += v.y; s.z += v.z; s.w += v.w;
        sq.x += v.x * v.x; sq.y += v.y * v.y; sq.z += v.z * v.z; sq.w += v.w * v.w;
    }
    float4 cr;
    cr.x = 0.5f * (s.x * s.x - sq.x);
    cr.y = 0.5f * (s.y * s.y - sq.y);
    cr.z = 0.5f * (s.z * s.z - sq.z);
    cr.w = 0.5f * (s.w * s.w - sq.w);
    uint2* orow = reinterpret_cast<uint2*>(ft0 + (size_t)n * CD);
    H4 pa, pb;
    pa.h2[0] = __floats2half2_rn(s.x, s.y);
    pa.h2[1] = __floats2half2_rn(s.z, s.w);
    pb.h2[0] = __floats2half2_rn(cr.x, cr.y);
    pb.h2[1] = __floats2half2_rn(cr.z, cr.w);
    orow[q] = pa.u;       // dims 4q..4q+3
    orow[8 + q] = pb.u;   // dims 32+4q..32+4q+3
}

// Conv level: per node n -> gather self row + sum of K neighbor rows (fp16 in),
// c = [n0+pool, n0*pool] (128), out = relu(c @ W + b) (64), optional L2-normalize.
// One wave owns one node's 64-dim row (lane = dim). P=4 nodes per wave per
// W-row LDS read. Node index is forced wave-uniform so adj/ids become s_loads.
template<bool NORM, typename OutT>
__launch_bounds__(256, 4)
__global__ void k_conv(const __half* __restrict__ ftin,
                       const int* __restrict__ ids,
                       const int* __restrict__ adj,
                       const float* __restrict__ W,
                       const float* __restrict__ bias,
                       OutT* __restrict__ ftout,
                       int nNodes) {
    __shared__ float Wl[2 * CD * CD];  // 32 KiB
    __shared__ float bl[CD];
    for (int i = threadIdx.x; i < 2 * CD * CD; i += blockDim.x) Wl[i] = W[i];
    if (threadIdx.x < CD) bl[threadIdx.x] = bias[threadIdx.x];
    __syncthreads();

    const int lane = threadIdx.x & 63;
    const int wave = __builtin_amdgcn_readfirstlane(threadIdx.x >> 6);
    const int wavesPerBlock = blockDim.x >> 6;
    constexpr int P = 4;
    const int batchNodes = wavesPerBlock * P;
    const int nBatches = (nNodes + batchNodes - 1) / batchNodes;

    for (int batch = blockIdx.x; batch < nBatches; batch += gridDim.x) {
        const int nodeBase =
            __builtin_amdgcn_readfirstlane(batch * batchNodes + wave * P);
        float c0[P], c1[P], acc[P];
#pragma unroll
        for (int p = 0; p < P; ++p) {
            int n = nodeBase + p;  // wave-uniform (SGPR)
            float n0 = 0.f, pool = 0.f;
            if (n < nNodes) {  // uniform branch
                int id = ids[n];  // s_load
                n0 = __half2float(ftin[(size_t)id * CD + lane]);
                const int* arow = adj + (size_t)n * CK;  // uniform ptr -> s_load row
                float p0 = 0.f, p1 = 0.f, p2 = 0.f, p3 = 0.f;
#pragma unroll
                for (int k = 0; k < CK; k += 4) {
                    p0 += __half2float(ftin[(size_t)arow[k + 0] * CD + lane]);
                    p1 += __half2float(ftin[(size_t)arow[k + 1] * CD + lane]);
                    p2 += __half2float(ftin[(size_t)arow[k + 2] * CD + lane]);
                    p3 += __half2float(ftin[(size_t)arow[k + 3] * CD + lane]);
                }
                pool = (p0 + p1) + (p2 + p3);
            }
            c0[p] = n0 + pool;   // rows 0..63 of conv vector (this lane's dim)
            c1[p] = n0 * pool;   // rows 64..127
            acc[p] = bl[lane];
        }
        // out[j] = b[j] + sum_i c[i] * W[i][j]; lane j accumulates its column.
#pragma unroll 8
        for (int i = 0; i < CD; ++i) {
            float w0 = Wl[i * CD + lane];
            float w1 = Wl[(CD + i) * CD + lane];
#pragma unroll
            for (int p = 0; p < P; ++p) {
                acc[p] = fmaf(lane_bcast(c0[p], i), w0, acc[p]);
                acc[p] = fmaf(lane_bcast(c1[p], i), w1, acc[p]);
            }
        }
#pragma unroll
        for (int p = 0; p < P; ++p) {
            int n = nodeBase + p;
            if (n >= nNodes) continue;
            float z = fmaxf(acc[p], 0.f);
            if (NORM) {
                float ss = z * z;
#pragma unroll
                for (int off = 32; off >= 1; off >>= 1) ss += __shfl_xor(ss, off);
                float nrm = fmaxf(sqrtf(ss), CEPS);
                ftout[(size_t)n * CD + lane] = (OutT)(z / nrm);
            } else {
                ftout[(size_t)n * CD + lane] = (OutT)z;
            }
        }
    }
}

extern "C" void kernel_launch(void* const* d_in, const int* in_sizes, int n_in,
                              void* d_out, int out_size, void* d_ws, size_t ws_size,
                              hipStream_t stream) {
    const float* node_feats  = (const float*)d_in[0];
    const int*   node_l1_ids = (const int*)d_in[1];
    const int*   adj1        = (const int*)d_in[2];
    const int*   node2_pos   = (const int*)d_in[3];
    const int*   adj2        = (const int*)d_in[4];
    const float* W1          = (const float*)d_in[5];
    const float* b1          = (const float*)d_in[6];
    const float* W2          = (const float*)d_in[7];
    const float* b2          = (const float*)d_in[8];
    float* out = (float*)d_out;

    __half* ft0 = (__half*)d_ws;                  // CN0*CD fp16 = 25.6 MB
    __half* ft1 = ft0 + (size_t)CN0 * CD;         // CN1*CD fp16 = 12.8 MB

    int t1 = CN0 * 8;
    k_lv0<<<(t1 + 255) / 256, 256, 0, stream>>>(node_feats, ft0);
    k_conv<false, __half><<<2048, 256, 0, stream>>>(ft0, node_l1_ids, adj1, W1, b1, ft1, CN1);
    k_conv<true, float><<<2048, 256, 0, stream>>>(ft1, node2_pos, adj2, W2, b2, out, CN2);
}